// Round 2
// baseline (272.853 us; speedup 1.0000x reference)
//
#include <hip/hip_runtime.h>
#include <math.h>

// Fused SegmentGatingNetwork: x[16384,1024] -> tanh(x@W1+b1)[.,256] -> @W2+b2 -> logits[.,64]
// -> top-2 softmax scatter -> gates. One kernel: 64 tokens per block, full hidden dim resident.
// fp32 vector (no fp32 MFMA on CDNA4). fmaf order over k kept ascending == previous passing kernel.

#define DM 1024
#define DH 256
#define NE 64
#define TK 32
#define NCH (DM / TK)   // 32 chunks
#define TM 64           // tokens per block

struct PhaseA {
    float xs[2][TK][68];   // [buf][k][tok(64)+pad]  17408 B  (transposed x tile)
    float ws[2][TK][DH];   // [buf][k][hid]          65536 B
};
struct PhaseB {
    float hs[TM][260];     // [tok][hid+pad]         66560 B  (pad 260: 2-way banks on bcast cols)
    float ls[TM][68];      // [tok][expert+pad]      17408 B
};

__global__ __launch_bounds__(256, 1)
void fused_gating_kernel(const float* __restrict__ x, const float* __restrict__ W1,
                         const float* __restrict__ b1, const float* __restrict__ W2,
                         const float* __restrict__ b2, float* __restrict__ gates,
                         float* __restrict__ logits_out) {
    __shared__ union { PhaseA a; PhaseB b; } u;   // 83968 B
    __shared__ float w2s[DH][NE];                 // 65536 B resident all kernel; total 146 KB

    const int tid = threadIdx.x;
    const int t0 = blockIdx.x * TM;

    // compute mapping: 8 tok x 8 hid per thread; wave w covers hids w*64..w*64+63
    const int tg = tid & 7;    // toks tg*8..+7   (8-way broadcast groups on 'a' reads)
    const int hg = tid >> 3;   // hids hg*8..+7   (2-way banks on 'b' reads: free)

    // x staging mapping: per chunk thread loads x[tok][xk..xk+7]
    const int xtok = tid >> 2;        // 0..63
    const int xk   = (tid & 3) * 8;   // 0,8,16,24
    const float* xg = x + (size_t)(t0 + xtok) * DM + xk;

    // ---- one-time: W2 -> LDS (coalesced, contiguous 64 KB) ----
#pragma unroll
    for (int j = 0; j < 16; j++) {
        int slot = tid + j * 256;  // 0..4095 float4 slots
        *(float4*)&w2s[slot >> 4][(slot & 15) * 4] = *(const float4*)(W2 + (size_t)slot * 4);
    }

    float acc[8][8];
#pragma unroll
    for (int i = 0; i < 8; i++)
#pragma unroll
        for (int j = 0; j < 8; j++) acc[i][j] = 0.f;

    // ---- prologue: stage chunk 0 into buf 0 ----
    {
        float4 v0 = *(const float4*)(xg);
        float4 v1 = *(const float4*)(xg + 4);
        float4 wv[8];
#pragma unroll
        for (int j = 0; j < 8; j++) {
            int slot = tid + j * 256;  // 0..2047
            wv[j] = *(const float4*)(W1 + (size_t)(slot >> 6) * DH + (slot & 63) * 4);
        }
        u.a.xs[0][xk + 0][xtok] = v0.x;
        u.a.xs[0][xk + 1][xtok] = v0.y;
        u.a.xs[0][xk + 2][xtok] = v0.z;
        u.a.xs[0][xk + 3][xtok] = v0.w;
        u.a.xs[0][xk + 4][xtok] = v1.x;
        u.a.xs[0][xk + 5][xtok] = v1.y;
        u.a.xs[0][xk + 6][xtok] = v1.z;
        u.a.xs[0][xk + 7][xtok] = v1.w;
#pragma unroll
        for (int j = 0; j < 8; j++) {
            int slot = tid + j * 256;
            *(float4*)&u.a.ws[0][slot >> 6][(slot & 63) * 4] = wv[j];
        }
    }
    __syncthreads();

    // ---- main loop: double-buffered; prefetch issued BEFORE compute, LDS-written after ----
    int buf = 0;
    for (int c = 0; c < NCH; c++) {
        float4 v0, v1, wv[8];
        const bool pre = (c + 1 < NCH);
        if (pre) {
            const int k0n = (c + 1) * TK;
            v0 = *(const float4*)(xg + k0n);
            v1 = *(const float4*)(xg + k0n + 4);
#pragma unroll
            for (int j = 0; j < 8; j++) {
                int slot = tid + j * 256;
                wv[j] = *(const float4*)(W1 + (size_t)(k0n + (slot >> 6)) * DH + (slot & 63) * 4);
            }
        }

        const float (*__restrict__ xsb)[68] = u.a.xs[buf];
        const float (*__restrict__ wsb)[DH] = u.a.ws[buf];
#pragma unroll 4
        for (int kk = 0; kk < TK; kk++) {
            float4 a0 = *(const float4*)&xsb[kk][tg * 8];
            float4 a1 = *(const float4*)&xsb[kk][tg * 8 + 4];
            float4 b0 = *(const float4*)&wsb[kk][hg * 8];
            float4 b1 = *(const float4*)&wsb[kk][hg * 8 + 4];
            float av[8] = {a0.x, a0.y, a0.z, a0.w, a1.x, a1.y, a1.z, a1.w};
            float bv[8] = {b0.x, b0.y, b0.z, b0.w, b1.x, b1.y, b1.z, b1.w};
#pragma unroll
            for (int i = 0; i < 8; i++)
#pragma unroll
                for (int j = 0; j < 8; j++)
                    acc[i][j] = fmaf(av[i], bv[j], acc[i][j]);
        }

        if (pre) {
            const int nb = buf ^ 1;
            u.a.xs[nb][xk + 0][xtok] = v0.x;
            u.a.xs[nb][xk + 1][xtok] = v0.y;
            u.a.xs[nb][xk + 2][xtok] = v0.z;
            u.a.xs[nb][xk + 3][xtok] = v0.w;
            u.a.xs[nb][xk + 4][xtok] = v1.x;
            u.a.xs[nb][xk + 5][xtok] = v1.y;
            u.a.xs[nb][xk + 6][xtok] = v1.z;
            u.a.xs[nb][xk + 7][xtok] = v1.w;
#pragma unroll
            for (int j = 0; j < 8; j++) {
                int slot = tid + j * 256;
                *(float4*)&u.a.ws[nb][slot >> 6][(slot & 63) * 4] = wv[j];
            }
        }
        __syncthreads();
        buf ^= 1;
    }
    // loop-ending barrier guarantees all reads of u.a are done -> safe to write u.b

    // ---- phase A epilogue: bias + tanh -> hs ----
    {
        float4 bb0 = *(const float4*)(b1 + hg * 8);
        float4 bb1 = *(const float4*)(b1 + hg * 8 + 4);
        float bias[8] = {bb0.x, bb0.y, bb0.z, bb0.w, bb1.x, bb1.y, bb1.z, bb1.w};
#pragma unroll
        for (int i = 0; i < 8; i++) {
            float4 h0, h1;
            h0.x = tanhf(acc[i][0] + bias[0]);
            h0.y = tanhf(acc[i][1] + bias[1]);
            h0.z = tanhf(acc[i][2] + bias[2]);
            h0.w = tanhf(acc[i][3] + bias[3]);
            h1.x = tanhf(acc[i][4] + bias[4]);
            h1.y = tanhf(acc[i][5] + bias[5]);
            h1.z = tanhf(acc[i][6] + bias[6]);
            h1.w = tanhf(acc[i][7] + bias[7]);
            *(float4*)&u.b.hs[tg * 8 + i][hg * 8]     = h0;
            *(float4*)&u.b.hs[tg * 8 + i][hg * 8 + 4] = h1;
        }
    }
    __syncthreads();

    // ---- phase B: logits = hs @ W2 (4 tok x 4 exp per thread) ----
    {
        const int ty = tid >> 4;   // toks ty*4..+3
        const int tx = tid & 15;   // exps tx*4..+3
        float lacc[4][4] = {{0.f}};
        for (int k = 0; k < DH; k += 4) {
            float am[4][4];
#pragma unroll
            for (int i = 0; i < 4; i++) {
                float4 t = *(const float4*)&u.b.hs[ty * 4 + i][k];
                am[i][0] = t.x; am[i][1] = t.y; am[i][2] = t.z; am[i][3] = t.w;
            }
#pragma unroll
            for (int kk = 0; kk < 4; kk++) {
                float4 bw = *(const float4*)&w2s[k + kk][tx * 4];
#pragma unroll
                for (int i = 0; i < 4; i++) {
                    lacc[i][0] = fmaf(am[i][kk], bw.x, lacc[i][0]);
                    lacc[i][1] = fmaf(am[i][kk], bw.y, lacc[i][1]);
                    lacc[i][2] = fmaf(am[i][kk], bw.z, lacc[i][2]);
                    lacc[i][3] = fmaf(am[i][kk], bw.w, lacc[i][3]);
                }
            }
        }
#pragma unroll
        for (int i = 0; i < 4; i++) {
            float4 o = {lacc[i][0], lacc[i][1], lacc[i][2], lacc[i][3]};
            *(float4*)&u.b.ls[ty * 4 + i][tx * 4] = o;
        }
    }
    __syncthreads();

    // ---- gating: 4 waves x 16 tokens; lane = expert ----
    {
        const int wave = tid >> 6;
        const int lane = tid & 63;
        const float b2v = b2[lane];
#pragma unroll 1
        for (int t = 0; t < 16; t++) {
            const int tok = wave * 16 + t;
            const float lg = u.b.ls[tok][lane] + b2v;

            // top-1 (lower index wins ties, matching jax.lax.top_k)
            float m1 = lg; int i1 = lane;
#pragma unroll
            for (int off = 32; off; off >>= 1) {
                float om = __shfl_xor(m1, off, 64);
                int oi = __shfl_xor(i1, off, 64);
                if (om > m1 || (om == m1 && oi < i1)) { m1 = om; i1 = oi; }
            }
            // top-2
            float l2 = (lane == i1) ? -INFINITY : lg;
            float m2 = l2; int i2 = lane;
#pragma unroll
            for (int off = 32; off; off >>= 1) {
                float om = __shfl_xor(m2, off, 64);
                int oi = __shfl_xor(i2, off, 64);
                if (om > m2 || (om == m2 && oi < i2)) { m2 = om; i2 = oi; }
            }
            float e = __expf(m2 - m1);
            float inv = 1.f / (1.f + e);
            float g = (lane == i1) ? inv : ((lane == i2) ? e * inv : 0.f);
            size_t row = (size_t)(t0 + tok) * NE;
            gates[row + lane] = g;
            logits_out[row + lane] = lg;
        }
    }
}

extern "C" void kernel_launch(void* const* d_in, const int* in_sizes, int n_in,
                              void* d_out, int out_size, void* d_ws, size_t ws_size,
                              hipStream_t stream) {
    const float* x  = (const float*)d_in[0];
    const float* W1 = (const float*)d_in[1];
    const float* b1 = (const float*)d_in[2];
    const float* W2 = (const float*)d_in[3];
    const float* b2 = (const float*)d_in[4];

    const int T = in_sizes[0] / DM;   // 16384
    float* gates  = (float*)d_out;
    float* logits = (float*)d_out + (size_t)T * NE;

    fused_gating_kernel<<<T / TM, 256, 0, stream>>>(x, W1, b1, W2, b2, gates, logits);
}

// Round 3
// 182.556 us; speedup vs baseline: 1.4946x; 1.4946x over previous
//
#include <hip/hip_runtime.h>
#include <math.h>

// SegmentGatingNetwork, MFMA path.
// GEMM1 (16384x1024 @ 1024x256) via 3-plane truncated-bf16 split + 6 MFMA products
// (hh,hm,mh,hl,lh,mm) -> fp32-equivalent accuracy (~2^-24 rel), 6x8.59=51.5 GF at bf16 MFMA rate.
// GEMM2+top2 gating: fp32 VALU kernel (0.54 GF), logic identical to the R1 passing kernel.

#define DM 1024
#define DH 256
#define NE 64
#define BM 64
#define BN 128
#define BK 64
#define NCH (DM / BK)   // 16

typedef __attribute__((ext_vector_type(8))) short bf16x8;
typedef __attribute__((ext_vector_type(4))) float f32x4;

__device__ __forceinline__ unsigned fbits(float f) { return __float_as_uint(f); }
__device__ __forceinline__ float topf(unsigned u) { return __uint_as_float(u & 0xFFFF0000u); }

// truncated 3-plane split: v = top16(h) + top16(m) + top16(l) + O(2^-24 * |v|)
__device__ __forceinline__ void split3(float v, unsigned& h, unsigned& m, unsigned& l) {
    h = fbits(v);
    float r1 = v - topf(h);
    m = fbits(r1);
    float r2 = r1 - topf(m);
    l = fbits(r2);
}
// pack two bf16 (from fp32 bit patterns) into one dword: lo half = first (even k)
__device__ __forceinline__ unsigned packpair(unsigned a, unsigned b) {
    return (a >> 16) | (b & 0xFFFF0000u);
}

// LDS layout (fragment-order, every 1KB block = one wave's 64x16B fragments):
//   A block(p,kc,ms):          ((p*2+kc)*4 + ms)*1024            p=plane, kc=k-chunk(32), ms=m-subtile(16)
//   B block(p,nt,kc): 24576 + ((p*8+nt)*2 + kc)*1024             nt=n-subtile(16)
// fragment lane L: A: m = ms*16+(L&15), k = kc*32+(L>>4)*8+j ; B: n = nt*16+(L&15), same k.

__global__ __launch_bounds__(256, 2)
void gemm1_mfma(const float* __restrict__ x, const float* __restrict__ W1,
                const float* __restrict__ b1, float* __restrict__ h) {
    __shared__ __align__(16) char lds[73728];   // 24KB A planes + 48KB B planes

    const int tid  = threadIdx.x;
    const int t0   = blockIdx.x * BM;
    const int n0   = blockIdx.y * BN;
    const int lane = tid & 63;
    const int wave = tid >> 6;
    const int wm   = wave >> 1;   // token half (32)
    const int wn   = wave & 1;    // hid half (64)

    // A staging map: thread -> token row, k-fragment pair
    const int atok = tid >> 2;        // 0..63
    const int akb  = tid & 3;         // kq for both fragments (kc=0 and kc=1)
    // B staging map: thread -> n15 lane, row-pair index
    const int bnb  = tid & 15;        // n mod 16  (spreads LDS banks)
    const int brp  = tid >> 4;        // 0..15 row-pair base

    f32x4 acc[2][4];
#pragma unroll
    for (int i = 0; i < 2; i++)
#pragma unroll
        for (int j = 0; j < 4; j++) acc[i][j] = (f32x4){0.f, 0.f, 0.f, 0.f};

    for (int c = 0; c < NCH; c++) {
        const int kbase = c * BK;

        // ---- issue global loads (consumed after barrier) ----
        const float* xrow = x + (size_t)(t0 + atok) * DM + kbase + akb * 8;
        float4 a0 = *(const float4*)(xrow);
        float4 a1 = *(const float4*)(xrow + 4);
        float4 a2 = *(const float4*)(xrow + 32);
        float4 a3 = *(const float4*)(xrow + 36);

        float wv[2][2][4][2];
#pragma unroll
        for (int pr = 0; pr < 2; pr++) {
            const int r0 = brp * 2 + pr * 32;
            const float* wr0 = W1 + (size_t)(kbase + r0) * DH + n0;
            const float* wr1 = wr0 + DH;
#pragma unroll
            for (int pn = 0; pn < 2; pn++)
#pragma unroll
                for (int g = 0; g < 4; g++) {
                    const int nl = bnb + pn * 64 + g * 16;
                    wv[pr][pn][g][0] = wr0[nl];
                    wv[pr][pn][g][1] = wr1[nl];
                }
        }

        __syncthreads();   // previous chunk's fragment reads complete

        // ---- A: convert 2 fragments (kc=0,1; kq=akb) and write 3 planes each ----
        {
            float v[2][8] = {{a0.x, a0.y, a0.z, a0.w, a1.x, a1.y, a1.z, a1.w},
                             {a2.x, a2.y, a2.z, a2.w, a3.x, a3.y, a3.z, a3.w}};
            const int laneoff = (akb * 16 + (atok & 15)) * 16;
            const int msoff   = (atok >> 4) * 1024;
#pragma unroll
            for (int kc = 0; kc < 2; kc++) {
                unsigned hb[8], mb[8], lb[8];
#pragma unroll
                for (int j = 0; j < 8; j++) split3(v[kc][j], hb[j], mb[j], lb[j]);
                uint4 dh = {packpair(hb[0], hb[1]), packpair(hb[2], hb[3]),
                            packpair(hb[4], hb[5]), packpair(hb[6], hb[7])};
                uint4 dm = {packpair(mb[0], mb[1]), packpair(mb[2], mb[3]),
                            packpair(mb[4], mb[5]), packpair(mb[6], mb[7])};
                uint4 dl = {packpair(lb[0], lb[1]), packpair(lb[2], lb[3]),
                            packpair(lb[4], lb[5]), packpair(lb[6], lb[7])};
                *(uint4*)(lds + (0 * 2 + kc) * 4096 + msoff + laneoff) = dh;
                *(uint4*)(lds + (1 * 2 + kc) * 4096 + msoff + laneoff) = dm;
                *(uint4*)(lds + (2 * 2 + kc) * 4096 + msoff + laneoff) = dl;
            }
        }

        // ---- B: convert k-pairs, scatter b32 dwords into fragment slots ----
        {
            char* bbase = lds + 24576;
#pragma unroll
            for (int pr = 0; pr < 2; pr++) {
                const int r0 = brp * 2 + pr * 32;
                const int kc = r0 >> 5;
                const int kk = r0 & 31;
                const int kq = kk >> 3;
                const int d4 = (kk >> 1) & 3;
                const int slotoff = (kq * 16 + bnb) * 16 + d4 * 4;
#pragma unroll
                for (int pn = 0; pn < 2; pn++)
#pragma unroll
                    for (int g = 0; g < 4; g++) {
                        const int nt = (bnb + pn * 64 + g * 16) >> 4;
                        unsigned h0, m0, l0, h1, m1, l1;
                        split3(wv[pr][pn][g][0], h0, m0, l0);
                        split3(wv[pr][pn][g][1], h1, m1, l1);
                        *(unsigned*)(bbase + ((0 * 8 + nt) * 2 + kc) * 1024 + slotoff) = packpair(h0, h1);
                        *(unsigned*)(bbase + ((1 * 8 + nt) * 2 + kc) * 1024 + slotoff) = packpair(m0, m1);
                        *(unsigned*)(bbase + ((2 * 8 + nt) * 2 + kc) * 1024 + slotoff) = packpair(l0, l1);
                    }
            }
        }

        __syncthreads();

        // ---- MFMA: 6 plane-products per (ms,nt) per kc ----
#pragma unroll
        for (int kc = 0; kc < 2; kc++) {
            bf16x8 af[3][2], bfr[3][4];
#pragma unroll
            for (int p = 0; p < 3; p++)
#pragma unroll
                for (int ms = 0; ms < 2; ms++)
                    af[p][ms] = *(const bf16x8*)(lds + (p * 2 + kc) * 4096 + (wm * 2 + ms) * 1024 + lane * 16);
#pragma unroll
            for (int p = 0; p < 3; p++)
#pragma unroll
                for (int nt = 0; nt < 4; nt++)
                    bfr[p][nt] = *(const bf16x8*)(lds + 24576 + ((p * 8 + wn * 4 + nt) * 2 + kc) * 1024 + lane * 16);
#pragma unroll
            for (int ms = 0; ms < 2; ms++)
#pragma unroll
                for (int nt = 0; nt < 4; nt++) {
                    f32x4 a = acc[ms][nt];
                    a = __builtin_amdgcn_mfma_f32_16x16x32_bf16(af[0][ms], bfr[0][nt], a, 0, 0, 0);
                    a = __builtin_amdgcn_mfma_f32_16x16x32_bf16(af[0][ms], bfr[1][nt], a, 0, 0, 0);
                    a = __builtin_amdgcn_mfma_f32_16x16x32_bf16(af[1][ms], bfr[0][nt], a, 0, 0, 0);
                    a = __builtin_amdgcn_mfma_f32_16x16x32_bf16(af[0][ms], bfr[2][nt], a, 0, 0, 0);
                    a = __builtin_amdgcn_mfma_f32_16x16x32_bf16(af[2][ms], bfr[0][nt], a, 0, 0, 0);
                    a = __builtin_amdgcn_mfma_f32_16x16x32_bf16(af[1][ms], bfr[1][nt], a, 0, 0, 0);
                    acc[ms][nt] = a;
                }
        }
    }

    // ---- epilogue: bias + tanh -> h (C/D layout: col=lane&15, row=(lane>>4)*4+reg) ----
    const int mrow = (lane >> 4) * 4;
    const int ncol = lane & 15;
#pragma unroll
    for (int ms = 0; ms < 2; ms++) {
        const int tokb = t0 + wm * 32 + ms * 16 + mrow;
#pragma unroll
        for (int nt = 0; nt < 4; nt++) {
            const int ng = n0 + wn * 64 + nt * 16 + ncol;
            const float bias = b1[ng];
#pragma unroll
            for (int r = 0; r < 4; r++)
                h[(size_t)(tokb + r) * DH + ng] = tanhf(acc[ms][nt][r] + bias);
        }
    }
}

// ---------------- GEMM2 + top-2 softmax gating ----------------
// 64 tok/block, hs tile in LDS (66.5KB -> 2 blocks/CU), W2 streamed from L2.
__global__ __launch_bounds__(256, 2)
void gate_kernel(const float* __restrict__ h, const float* __restrict__ W2,
                 const float* __restrict__ b2, float* __restrict__ gates,
                 float* __restrict__ logits_out) {
    __shared__ float hs[64][260];

    const int tid = threadIdx.x;
    const int t0 = blockIdx.x * 64;

    // load h tile, coalesced
#pragma unroll
    for (int j = 0; j < 16; j++) {
        int slot = tid + j * 256;         // 0..4095 float4 slots
        int row = slot >> 6, c4 = slot & 63;
        *(float4*)&hs[row][c4 * 4] = *(const float4*)(h + (size_t)(t0 + row) * DH + c4 * 4);
    }
    __syncthreads();

    const int ty = tid >> 4;   // toks ty*4..+3
    const int tx = tid & 15;   // exps tx*4..+3
    float acc[4][4];
#pragma unroll
    for (int i = 0; i < 4; i++)
#pragma unroll
        for (int j = 0; j < 4; j++) acc[i][j] = 0.f;

    for (int k = 0; k < DH; k += 4) {
        float4 am[4];
#pragma unroll
        for (int i = 0; i < 4; i++) am[i] = *(const float4*)&hs[ty * 4 + i][k];
        float4 w[4];
#pragma unroll
        for (int kk = 0; kk < 4; kk++) w[kk] = *(const float4*)(W2 + (size_t)(k + kk) * NE + tx * 4);
#pragma unroll
        for (int kk = 0; kk < 4; kk++) {
            float a0 = am[0][kk], a1 = am[1][kk], a2 = am[2][kk], a3 = am[3][kk];
            acc[0][0] = fmaf(a0, w[kk].x, acc[0][0]); acc[0][1] = fmaf(a0, w[kk].y, acc[0][1]);
            acc[0][2] = fmaf(a0, w[kk].z, acc[0][2]); acc[0][3] = fmaf(a0, w[kk].w, acc[0][3]);
            acc[1][0] = fmaf(a1, w[kk].x, acc[1][0]); acc[1][1] = fmaf(a1, w[kk].y, acc[1][1]);
            acc[1][2] = fmaf(a1, w[kk].z, acc[1][2]); acc[1][3] = fmaf(a1, w[kk].w, acc[1][3]);
            acc[2][0] = fmaf(a2, w[kk].x, acc[2][0]); acc[2][1] = fmaf(a2, w[kk].y, acc[2][1]);
            acc[2][2] = fmaf(a2, w[kk].z, acc[2][2]); acc[2][3] = fmaf(a2, w[kk].w, acc[2][3]);
            acc[3][0] = fmaf(a3, w[kk].x, acc[3][0]); acc[3][1] = fmaf(a3, w[kk].y, acc[3][1]);
            acc[3][2] = fmaf(a3, w[kk].z, acc[3][2]); acc[3][3] = fmaf(a3, w[kk].w, acc[3][3]);
        }
    }

    __syncthreads();   // all hs reads done -> safe to overlay
    float* ls = &hs[0][0];   // reuse as [64][68]
#pragma unroll
    for (int i = 0; i < 4; i++) {
        float4 o = {acc[i][0], acc[i][1], acc[i][2], acc[i][3]};
        *(float4*)&ls[(ty * 4 + i) * 68 + tx * 4] = o;
    }
    __syncthreads();

    // gating: 4 waves x 16 tokens; lane = expert (identical logic to R1 passing kernel)
    const int wave = tid >> 6;
    const int lane = tid & 63;
    const float b2v = b2[lane];
#pragma unroll 1
    for (int t = 0; t < 16; t++) {
        const int tok = wave * 16 + t;
        const float lg = ls[tok * 68 + lane] + b2v;

        float m1 = lg; int i1 = lane;
#pragma unroll
        for (int off = 32; off; off >>= 1) {
            float om = __shfl_xor(m1, off, 64);
            int oi = __shfl_xor(i1, off, 64);
            if (om > m1 || (om == m1 && oi < i1)) { m1 = om; i1 = oi; }
        }
        float l2 = (lane == i1) ? -INFINITY : lg;
        float m2 = l2; int i2 = lane;
#pragma unroll
        for (int off = 32; off; off >>= 1) {
            float om = __shfl_xor(m2, off, 64);
            int oi = __shfl_xor(i2, off, 64);
            if (om > m2 || (om == m2 && oi < i2)) { m2 = om; i2 = oi; }
        }
        float e = __expf(m2 - m1);
        float inv = 1.f / (1.f + e);
        float g = (lane == i1) ? inv : ((lane == i2) ? e * inv : 0.f);
        size_t row = (size_t)(t0 + tok) * NE;
        gates[row + lane] = g;
        logits_out[row + lane] = lg;
    }
}

extern "C" void kernel_launch(void* const* d_in, const int* in_sizes, int n_in,
                              void* d_out, int out_size, void* d_ws, size_t ws_size,
                              hipStream_t stream) {
    const float* x  = (const float*)d_in[0];
    const float* W1 = (const float*)d_in[1];
    const float* b1 = (const float*)d_in[2];
    const float* W2 = (const float*)d_in[3];
    const float* b2 = (const float*)d_in[4];

    const int T = in_sizes[0] / DM;   // 16384
    float* hbuf   = (float*)d_ws;     // T*256 fp32 = 16.78 MB
    float* gates  = (float*)d_out;
    float* logits = (float*)d_out + (size_t)T * NE;

    gemm1_mfma<<<dim3(T / BM, 2), 256, 0, stream>>>(x, W1, b1, hbuf);
    gate_kernel<<<T / 64, 256, 0, stream>>>(hbuf, W2, b2, gates, logits);
}

// Round 4
// 153.729 us; speedup vs baseline: 1.7749x; 1.1875x over previous
//
#include <hip/hip_runtime.h>
#include <math.h>

// SegmentGatingNetwork, MFMA path v2.
// prep: W1,W2 -> 3 truncated-bf16 planes each, stored in MFMA B-fragment order (d_ws).
// gemm1: x split3 in-kernel (LDS dbuf), B-frags straight from global (L2-resident planes),
//        6 plane-products (hh,hm,mh,hl,lh,mm) per tile -> fp32-equivalent, h fp32 to d_ws.
// gate:  A-frags built in-register from h (split3), B = W2 planes, MFMA logits,
//        in-register top-2 (local top2 + 16-lane butterfly merge), softmax, scatter.

#define DM 1024
#define DH 256
#define NE 64
#define BM 64
#define BN 128
#define BK 32

// d_ws layout (bytes)
#define W1P_OFF 0                 // 3 planes * 131072 dwords = 1572864 B
#define W1P_STRIDE 524288         // bytes per plane
#define W2P_OFF 1572864           // 3 planes * 8192 dwords = 98304 B
#define W2P_STRIDE 32768
#define H_OFF 1671168             // 16384*256*4 = 16777216 B

typedef __attribute__((ext_vector_type(8))) short bf16x8;
typedef __attribute__((ext_vector_type(4))) float f32x4;

__device__ __forceinline__ unsigned fbits(float f) { return __float_as_uint(f); }
__device__ __forceinline__ float topf(unsigned u) { return __uint_as_float(u & 0xFFFF0000u); }

// truncated 3-plane split: v == top16(h)+top16(m)+top16(l) exactly (8+8+8 mantissa bits)
__device__ __forceinline__ void split3(float v, unsigned& h, unsigned& m, unsigned& l) {
    h = fbits(v);
    float r1 = v - topf(h);
    m = fbits(r1);
    float r2 = r1 - topf(m);
    l = fbits(r2);
}
// pack two bf16 (from fp32 bit patterns) into one dword: lo half = first (even k)
__device__ __forceinline__ unsigned packpair(unsigned a, unsigned b) {
    return (a >> 16) | (b & 0xFFFF0000u);
}
__device__ __forceinline__ bf16x8 as_bf(uint4 u) {
    union { uint4 a; bf16x8 b; } c; c.a = u; return c.b;
}

// Fragment conventions (empirically verified by R3 passing):
//   A-frag 16x16x32: m = lane&15, k = (lane>>4)*8 + j, dword q = k-pairs (2q,2q+1)
//   B-frag:          n = lane&15, same k mapping
//   C/D:             col(n) = lane&15, row(m) = (lane>>4)*4 + reg

// ---------------- prep: weight planes in B-fragment order ----------------
// W1 planes: flat dword idx = ((kc*16 + nt)*64 + L)*4 + q   (kc<32, nt<16)
// W2 planes: flat dword idx = ((kc*4  + nt)*64 + L)*4 + q   (kc<8,  nt<4)
__global__ __launch_bounds__(256)
void prep_planes(const float* __restrict__ W1, const float* __restrict__ W2,
                 char* __restrict__ ws) {
    unsigned* w1p = (unsigned*)(ws + W1P_OFF);
    unsigned* w2p = (unsigned*)(ws + W2P_OFF);
    const int gt = blockIdx.x * 256 + threadIdx.x;
    if (gt < 131072) {
        const int q = gt & 3, L = (gt >> 2) & 63, nt = (gt >> 8) & 15, kc = gt >> 12;
        const int n = nt * 16 + (L & 15);
        const int k0 = kc * 32 + ((L >> 4) & 3) * 8 + 2 * q;
        float v0 = W1[(size_t)k0 * DH + n];
        float v1 = W1[(size_t)(k0 + 1) * DH + n];
        unsigned h0, m0, l0, h1, m1, l1;
        split3(v0, h0, m0, l0);
        split3(v1, h1, m1, l1);
        w1p[0 * 131072 + gt] = packpair(h0, h1);
        w1p[1 * 131072 + gt] = packpair(m0, m1);
        w1p[2 * 131072 + gt] = packpair(l0, l1);
    } else {
        const int g2 = gt - 131072;
        if (g2 < 8192) {
            const int q = g2 & 3, L = (g2 >> 2) & 63, nt = (g2 >> 8) & 3, kc = g2 >> 10;
            const int n = nt * 16 + (L & 15);
            const int k0 = kc * 32 + ((L >> 4) & 3) * 8 + 2 * q;
            float v0 = W2[k0 * NE + n];
            float v1 = W2[(k0 + 1) * NE + n];
            unsigned h0, m0, l0, h1, m1, l1;
            split3(v0, h0, m0, l0);
            split3(v1, h1, m1, l1);
            w2p[0 * 8192 + g2] = packpair(h0, h1);
            w2p[1 * 8192 + g2] = packpair(m0, m1);
            w2p[2 * 8192 + g2] = packpair(l0, l1);
        }
    }
}

// x chunk -> 3 A-planes in LDS (fragment order). wb points at this thread's slot.
__device__ __forceinline__ void cvt_store(float4 a, float4 b, char* wb) {
    float v[8] = {a.x, a.y, a.z, a.w, b.x, b.y, b.z, b.w};
    unsigned hh[8], mm[8], ll[8];
#pragma unroll
    for (int j = 0; j < 8; j++) split3(v[j], hh[j], mm[j], ll[j]);
    uint4 dh = {packpair(hh[0], hh[1]), packpair(hh[2], hh[3]),
                packpair(hh[4], hh[5]), packpair(hh[6], hh[7])};
    uint4 dm = {packpair(mm[0], mm[1]), packpair(mm[2], mm[3]),
                packpair(mm[4], mm[5]), packpair(mm[6], mm[7])};
    uint4 dl = {packpair(ll[0], ll[1]), packpair(ll[2], ll[3]),
                packpair(ll[4], ll[5]), packpair(ll[6], ll[7])};
    *(uint4*)(wb + 0)    = dh;
    *(uint4*)(wb + 4096) = dm;
    *(uint4*)(wb + 8192) = dl;
}

// ---------------- GEMM1: h = tanh(x @ W1 + b1) ----------------
// 64 tok x 128 hid per block, BK=32, wave tile 64x32 (ms=4, nt=2). grid (256,2), 2 blocks/CU.
__global__ __launch_bounds__(256, 2)
void gemm1_mfma(const float* __restrict__ x, const char* __restrict__ w1p,
                const float* __restrict__ b1, float* __restrict__ h) {
    __shared__ __align__(16) char lds[2][12288];   // [buf][(p*4+ms)*1024 + L*16]

    const int tid  = threadIdx.x;
    const int lane = tid & 63;
    const int wave = tid >> 6;
    const int t0 = blockIdx.x * BM;
    const int n0 = blockIdx.y * BN;

    // staging map: thread -> (token, 8-k run)
    const int stok = tid >> 2;
    const int slr  = tid & 3;
    const int sms  = stok >> 4;
    const int sL   = slr * 16 + (stok & 15);
    char* wb0 = &lds[0][sms * 1024 + sL * 16];
    char* wb1 = &lds[1][sms * 1024 + sL * 16];
    const float* xg = x + (size_t)(t0 + stok) * DM + slr * 8;

    // this wave's B-frag base: nt_global = blockIdx.y*8 + wave*2 + nt2
    const char* btile = w1p + (size_t)(blockIdx.y * 8 + wave * 2) * 1024 + lane * 16;

    f32x4 acc[4][2];
#pragma unroll
    for (int i = 0; i < 4; i++)
#pragma unroll
        for (int j = 0; j < 2; j++) acc[i][j] = (f32x4){0.f, 0.f, 0.f, 0.f};

    // prologue: chunk 0
    {
        float4 xa = *(const float4*)(xg);
        float4 xb = *(const float4*)(xg + 4);
        cvt_store(xa, xb, wb0);
    }
    uint4 bc[3][2];
#pragma unroll
    for (int p = 0; p < 3; p++)
#pragma unroll
        for (int nt = 0; nt < 2; nt++)
            bc[p][nt] = *(const uint4*)(btile + p * W1P_STRIDE + nt * 1024);
    __syncthreads();

    for (int kc = 0; kc < 32; kc++) {
        const bool pre = (kc + 1) < 32;
        float4 xna, xnb;
        uint4 bn[3][2];
        if (pre) {
            xna = *(const float4*)(xg + (kc + 1) * 32);
            xnb = *(const float4*)(xg + (kc + 1) * 32 + 4);
#pragma unroll
            for (int p = 0; p < 3; p++)
#pragma unroll
                for (int nt = 0; nt < 2; nt++)
                    bn[p][nt] = *(const uint4*)(btile + p * W1P_STRIDE + (kc + 1) * 16384 + nt * 1024);
        }

        const char* abase = &lds[kc & 1][lane * 16];
        bf16x8 af[3][4];
#pragma unroll
        for (int p = 0; p < 3; p++)
#pragma unroll
            for (int ms = 0; ms < 4; ms++)
                af[p][ms] = *(const bf16x8*)(abase + (p * 4 + ms) * 1024);

#pragma unroll
        for (int ms = 0; ms < 4; ms++)
#pragma unroll
            for (int nt = 0; nt < 2; nt++) {
                f32x4 a = acc[ms][nt];
                a = __builtin_amdgcn_mfma_f32_16x16x32_bf16(af[0][ms], as_bf(bc[0][nt]), a, 0, 0, 0);
                a = __builtin_amdgcn_mfma_f32_16x16x32_bf16(af[0][ms], as_bf(bc[1][nt]), a, 0, 0, 0);
                a = __builtin_amdgcn_mfma_f32_16x16x32_bf16(af[1][ms], as_bf(bc[0][nt]), a, 0, 0, 0);
                a = __builtin_amdgcn_mfma_f32_16x16x32_bf16(af[0][ms], as_bf(bc[2][nt]), a, 0, 0, 0);
                a = __builtin_amdgcn_mfma_f32_16x16x32_bf16(af[2][ms], as_bf(bc[0][nt]), a, 0, 0, 0);
                a = __builtin_amdgcn_mfma_f32_16x16x32_bf16(af[1][ms], as_bf(bc[1][nt]), a, 0, 0, 0);
                acc[ms][nt] = a;
            }

        if (pre) {
            cvt_store(xna, xnb, (kc & 1) ? wb0 : wb1);
#pragma unroll
            for (int p = 0; p < 3; p++)
#pragma unroll
                for (int nt = 0; nt < 2; nt++) bc[p][nt] = bn[p][nt];
        }
        __syncthreads();
    }

    // epilogue: bias + tanh -> h fp32 (C/D layout)
    const int rq = lane >> 4;
    const int l15 = lane & 15;
#pragma unroll
    for (int nt = 0; nt < 2; nt++) {
        const int hid = n0 + (wave * 2 + nt) * 16 + l15;
        const float bias = b1[hid];
#pragma unroll
        for (int ms = 0; ms < 4; ms++) {
            const int tokb = t0 + ms * 16 + rq * 4;
#pragma unroll
            for (int r = 0; r < 4; r++)
                h[(size_t)(tokb + r) * DH + hid] = tanhf(acc[ms][nt][r] + bias);
        }
    }
}

// ---------------- gate: logits = h @ W2 + b2, top-2 softmax scatter ----------------
// 64 tok/block (4 independent waves x 16 tok), no LDS, no barriers. grid = 256.
__global__ __launch_bounds__(256)
void gate_kernel(const float* __restrict__ h, const char* __restrict__ w2p,
                 const float* __restrict__ b2, float* __restrict__ gates,
                 float* __restrict__ logits_out) {
    const int tid = threadIdx.x;
    const int lane = tid & 63;
    const int wave = tid >> 6;
    const int l15 = lane & 15;
    const int lq = lane >> 4;
    const int tok16 = blockIdx.x * 64 + wave * 16;

    const float* hb = h + (size_t)(tok16 + l15) * DH + lq * 8;
    const char* bt = w2p + lane * 16;

    f32x4 acc[4];
#pragma unroll
    for (int nt = 0; nt < 4; nt++) acc[nt] = (f32x4){0.f, 0.f, 0.f, 0.f};

    for (int kc = 0; kc < 8; kc++) {
        float4 f0 = *(const float4*)(hb + kc * 32);
        float4 f1 = *(const float4*)(hb + kc * 32 + 4);
        float v[8] = {f0.x, f0.y, f0.z, f0.w, f1.x, f1.y, f1.z, f1.w};
        unsigned hh[8], mm[8], ll[8];
#pragma unroll
        for (int j = 0; j < 8; j++) split3(v[j], hh[j], mm[j], ll[j]);
        uint4 ah = {packpair(hh[0], hh[1]), packpair(hh[2], hh[3]),
                    packpair(hh[4], hh[5]), packpair(hh[6], hh[7])};
        uint4 am = {packpair(mm[0], mm[1]), packpair(mm[2], mm[3]),
                    packpair(mm[4], mm[5]), packpair(mm[6], mm[7])};
        uint4 al = {packpair(ll[0], ll[1]), packpair(ll[2], ll[3]),
                    packpair(ll[4], ll[5]), packpair(ll[6], ll[7])};
        bf16x8 afh = as_bf(ah), afm = as_bf(am), afl = as_bf(al);
#pragma unroll
        for (int nt = 0; nt < 4; nt++) {
            const char* tb = bt + (kc * 4 + nt) * 1024;
            bf16x8 bh = *(const bf16x8*)(tb + 0 * W2P_STRIDE);
            bf16x8 bm = *(const bf16x8*)(tb + 1 * W2P_STRIDE);
            bf16x8 bl = *(const bf16x8*)(tb + 2 * W2P_STRIDE);
            f32x4 a = acc[nt];
            a = __builtin_amdgcn_mfma_f32_16x16x32_bf16(afh, bh, a, 0, 0, 0);
            a = __builtin_amdgcn_mfma_f32_16x16x32_bf16(afh, bm, a, 0, 0, 0);
            a = __builtin_amdgcn_mfma_f32_16x16x32_bf16(afm, bh, a, 0, 0, 0);
            a = __builtin_amdgcn_mfma_f32_16x16x32_bf16(afh, bl, a, 0, 0, 0);
            a = __builtin_amdgcn_mfma_f32_16x16x32_bf16(afl, bh, a, 0, 0, 0);
            a = __builtin_amdgcn_mfma_f32_16x16x32_bf16(afm, bm, a, 0, 0, 0);
            acc[nt] = a;
        }
    }

    float b2v[4];
#pragma unroll
    for (int nt = 0; nt < 4; nt++) b2v[nt] = b2[nt * 16 + l15];

    // per r: lane holds 4 experts of token tok16 + lq*4 + r; top-2 = local top2 + butterfly(16)
#pragma unroll
    for (int r = 0; r < 4; r++) {
        float v[4]; int e[4];
#pragma unroll
        for (int nt = 0; nt < 4; nt++) { v[nt] = acc[nt][r] + b2v[nt]; e[nt] = nt * 16 + l15; }

        float a1 = v[0], a2 = v[1]; int j1 = e[0], j2 = e[1];
        if (v[1] > v[0]) { a1 = v[1]; j1 = e[1]; a2 = v[0]; j2 = e[0]; }
#pragma unroll
        for (int t = 2; t < 4; t++) {
            if (v[t] > a1) { a2 = a1; j2 = j1; a1 = v[t]; j1 = e[t]; }
            else if (v[t] > a2) { a2 = v[t]; j2 = e[t]; }
        }
#pragma unroll
        for (int off = 1; off < 16; off <<= 1) {
            float ob1 = __shfl_xor(a1, off, 64); int oj1 = __shfl_xor(j1, off, 64);
            float ob2 = __shfl_xor(a2, off, 64); int oj2 = __shfl_xor(j2, off, 64);
            bool bw = (ob1 > a1) || (ob1 == a1 && oj1 < j1);
            float w1v = bw ? ob1 : a1; int w1i = bw ? oj1 : j1;
            float lv = bw ? a1 : ob1;  int li  = bw ? j1 : oj1;   // loser of top duel
            float rv = bw ? ob2 : a2;  int ri  = bw ? oj2 : j2;   // winner side's runner-up
            bool cw = (lv > rv) || (lv == rv && li < ri);
            a1 = w1v; j1 = w1i;
            a2 = cw ? lv : rv; j2 = cw ? li : ri;
        }
        float ex = __expf(a2 - a1);            // a2 <= a1: stable
        float inv = 1.f / (1.f + ex);
        float g1 = inv, g2 = ex * inv;

        const size_t row = (size_t)(tok16 + lq * 4 + r) * NE;
#pragma unroll
        for (int nt = 0; nt < 4; nt++) {
            float gv = (e[nt] == j1) ? g1 : ((e[nt] == j2) ? g2 : 0.f);
            gates[row + e[nt]] = gv;
            logits_out[row + e[nt]] = v[nt];
        }
    }
}

extern "C" void kernel_launch(void* const* d_in, const int* in_sizes, int n_in,
                              void* d_out, int out_size, void* d_ws, size_t ws_size,
                              hipStream_t stream) {
    const float* x  = (const float*)d_in[0];
    const float* W1 = (const float*)d_in[1];
    const float* b1 = (const float*)d_in[2];
    const float* W2 = (const float*)d_in[3];
    const float* b2 = (const float*)d_in[4];

    const int T = in_sizes[0] / DM;   // 16384
    char* ws = (char*)d_ws;
    float* hbuf = (float*)(ws + H_OFF);
    float* gates  = (float*)d_out;
    float* logits = (float*)d_out + (size_t)T * NE;

    prep_planes<<<(131072 + 8192) / 256, 256, 0, stream>>>(W1, W2, ws);
    gemm1_mfma<<<dim3(T / BM, 2), 256, 0, stream>>>(x, ws + W1P_OFF, b1, hbuf);
    gate_kernel<<<T / 64, 256, 0, stream>>>(hbuf, ws + W2P_OFF, b2, gates, logits);
}